// Round 13
// baseline (763.816 us; speedup 1.0000x reference)
//
#include <hip/hip_runtime.h>
#include <hip/hip_bf16.h>

typedef __attribute__((ext_vector_type(8))) short short8;
typedef __attribute__((ext_vector_type(4))) float f32x4;

__device__ __forceinline__ float bf2f(unsigned short u) {
    union { unsigned int i; float f; } c;
    c.i = ((unsigned int)u) << 16;
    return c.f;
}
__device__ __forceinline__ unsigned short f2bf(float f) {
    union { float f; unsigned int i; } c;
    c.f = f;
    unsigned int x = c.i;
    x += 0x7FFFu + ((x >> 16) & 1u);
    return (unsigned short)(x >> 16);
}
// tanh-form GELU via v_exp_f32/v_rcp_f32: |err| < 3.2e-3 abs.
__device__ __forceinline__ float gelu_fast(float x) {
    const float x2 = x * x;
    const float t = x * fmaf(0.0713548163f, x2, 1.5957691216f);
    const float e = __expf(t);
    const float r = __builtin_amdgcn_rcpf(e + 1.0f);
    return fmaf(-x, r, x);
}

#define NPART 64

// Last-block coef fold: partials -> [sc(W)|sh(W)]. Reads partials with
// coherent atomic-reads (cross-XCD safe); coef visible to next kernel via
// kernel-boundary flush.
__device__ __forceinline__ void coef_fold(float* part, const float* gArr,
                                          const float* bArr, float* coefOut,
                                          int W, float invN, int tid)
{
    for (int i = tid; i < W; i += 256) {
        float s = 0.f, q = 0.f;
        for (int r = 0; r < NPART; ++r) {
            s += atomicAdd(&part[(size_t)r * 2 * W + i], 0.0f);
            q += atomicAdd(&part[(size_t)r * 2 * W + W + i], 0.0f);
        }
        const float mean = s * invN;
        const float var  = q * invN - mean * mean;
        const float sc   = gArr[i] * rsqrtf(var + 1e-5f);
        coefOut[i] = sc;
        coefOut[W + i] = bArr[i] - mean * sc;
    }
}

// ---------------- fused GEMM: C[n,M] = f(A)[n,K] @ W[K,M] + bias ------------
// R11 64-row config. Hashed partial stats (blockIdx&63) + last-block ticket
// folds partials -> coef (removes 6 serial coef launches).
// XF: 0=bf16 pass, 1=fp32 cast, 2=BN+GELUfast,
//     3=BN + res1(bf16) + res2(fp32), side-writing transformed A to h3out.
template<int K, int M, int XF>
__global__ __launch_bounds__(256, (K > 256) ? 4 : 5)
void gemmf_kernel(const void* __restrict__ Av,
                  const float* __restrict__ pCoef,
                  const unsigned short* __restrict__ res1,
                  const float* __restrict__ res2,
                  unsigned short* __restrict__ h3out,
                  const unsigned short* __restrict__ Wp,
                  const float* __restrict__ bias,
                  float* __restrict__ part,          // [NPART][2*M] or null
                  unsigned short* __restrict__ C,
                  int nrows,
                  const float* __restrict__ gArr, const float* __restrict__ bArr,
                  float* __restrict__ coefOut, int* __restrict__ ticket,
                  float invN)
{
    constexpr int KS_TOT = K / 32;
    constexpr int NKC    = K / 128;
    constexpr int NCT    = M / 128;
    constexpr bool DBUF  = (K > 256);
    constexpr int NFRAG  = DBUF ? 32 : 4 * KS_TOT;
    __shared__ __align__(16) char smem[NFRAG * 1024 + ((NCT > 1) ? 16384 : 0)];
    __shared__ int lastFlag;
    char* cbuf = smem + ((NCT > 1) ? NFRAG * 1024 : 0);

    const int tid = threadIdx.x;
    const int l   = tid & 63, wv = tid >> 6;
    const int gr0 = blockIdx.x * 64;
    const int kq4 = l & 3, rloc = l >> 2;
    const int woff = ((kq4 * 16 + rloc) * 16) ^ (kq4 << 5);
    const int loff = (l * 16) ^ ((l >> 4) << 5);

    int rowg[4];
    bool rval[4];
    #pragma unroll
    for (int i = 0; i < 4; ++i) {
        int rg = gr0 + i * 16 + rloc;
        rval[i] = rg < nrows;
        rowg[i] = rval[i] ? rg : nrows - 1;
    }

    f32x4 acc[4][2];
    short8 breg[2][4];

    auto loadB = [&](int ct, int kcb) {
        #pragma unroll
        for (int c = 0; c < 2; ++c) {
            const int col = ct * 128 + (wv * 2 + c) * 16 + (l & 15);
            const unsigned short* bp = Wp + (size_t)col * K + kcb + (l >> 4) * 8;
            #pragma unroll
            for (int ks = 0; ks < 4; ++ks)
                breg[c][ks] = *(const short8*)(bp + ks * 32);
        }
    };

    auto xf2 = [&](short8 t, const float* sc8, const float* sh8) -> short8 {
        short8 val;
        #pragma unroll
        for (int j = 0; j < 8; ++j) {
            float v = fmaf(sc8[j], bf2f((unsigned short)t[j]), sh8[j]);
            val[j] = (short)f2bf(gelu_fast(v));
        }
        return val;
    };

    auto epilogue = [&](int ct) {
        const int lrow = l & 15, kg = l >> 4;
        __syncthreads();
        #pragma unroll
        for (int c = 0; c < 2; ++c) {
            const int col  = (wv * 2 + c) * 16 + lrow;
            const int gcol = ct * 128 + col;
            const float bc = bias[gcol];
            float s = 0.f, q = 0.f;
            #pragma unroll
            for (int r = 0; r < 4; ++r) {
                #pragma unroll
                for (int i = 0; i < 4; ++i) {
                    const int rl = r * 16 + kg * 4 + i;
                    const float v = acc[r][c][i] + bc;
                    if (gr0 + rl < nrows) { s += v; q += v * v; }
                    const int byte = rl * 256 + ((col * 2) ^ ((rl & 7) << 4));
                    *(unsigned short*)(cbuf + byte) = f2bf(v);
                }
            }
            s += __shfl_xor(s, 16); s += __shfl_xor(s, 32);
            q += __shfl_xor(q, 16); q += __shfl_xor(q, 32);
            if (kg == 0 && part != nullptr) {
                float* ps = part + (size_t)(blockIdx.x & (NPART - 1)) * (2 * M);
                atomicAdd(&ps[gcol], s);
                atomicAdd(&ps[M + gcol], q);
            }
        }
        __syncthreads();
        #pragma unroll
        for (int j = 0; j < 4; ++j) {
            const int lin = j * 256 + tid;
            const int rl = lin >> 4, chunk = lin & 15;
            const int row = gr0 + rl;
            if (row < nrows) {
                short8 vv = *(const short8*)(cbuf + rl * 256 + ((chunk * 16) ^ ((rl & 7) << 4)));
                *(short8*)(C + (size_t)row * M + ct * 128 + chunk * 8) = vv;
            }
        }
    };

    if constexpr (!DBUF) {
        #pragma unroll
        for (int h = 0; h < NKC; ++h) {
            const int kst = h * 4 + wv;
            const int c0k = kst * 32 + kq4 * 8;
            float sc8[8], sh8[8];
            if (XF >= 2) {
                #pragma unroll
                for (int j = 0; j < 8; ++j) {
                    sc8[j] = pCoef[c0k + j];
                    sh8[j] = pCoef[K + c0k + j];
                }
            }
            #pragma unroll
            for (int i = 0; i < 4; ++i) {
                const size_t eoff = (size_t)rowg[i] * K + c0k;
                short8 val;
                if (XF == 0) {
                    val = *(const short8*)((const unsigned short*)Av + eoff);
                } else if (XF == 1) {
                    const float* A = (const float*)Av;
                    f32x4 u0 = *(const f32x4*)(A + eoff);
                    f32x4 u1 = *(const f32x4*)(A + eoff + 4);
                    #pragma unroll
                    for (int j = 0; j < 4; ++j) {
                        val[j]     = (short)f2bf(u0[j]);
                        val[j + 4] = (short)f2bf(u1[j]);
                    }
                } else if (XF == 2) {
                    short8 t = *(const short8*)((const unsigned short*)Av + eoff);
                    val = xf2(t, sc8, sh8);
                } else {   // XF==3: h3 = bn(t4) + t2 + x, side-write
                    short8 t = *(const short8*)((const unsigned short*)Av + eoff);
                    short8 u = *(const short8*)(res1 + eoff);
                    f32x4 x0 = *(const f32x4*)(res2 + eoff);
                    f32x4 x1 = *(const f32x4*)(res2 + eoff + 4);
                    #pragma unroll
                    for (int j = 0; j < 8; ++j) {
                        float v = fmaf(sc8[j], bf2f((unsigned short)t[j]), sh8[j]);
                        v += bf2f((unsigned short)u[j]) + ((j < 4) ? x0[j] : x1[j - 4]);
                        val[j] = (short)f2bf(v);
                    }
                    if (rval[i]) *(short8*)(h3out + eoff) = val;
                }
                *(short8*)(smem + (i * KS_TOT + kst) * 1024 + woff) = val;
            }
        }
        __syncthreads();
        #pragma unroll
        for (int ct = 0; ct < NCT; ++ct) {
            #pragma unroll
            for (int r = 0; r < 4; ++r)
                #pragma unroll
                for (int c = 0; c < 2; ++c) acc[r][c] = f32x4{0.f, 0.f, 0.f, 0.f};
            #pragma unroll
            for (int kc = 0; kc < NKC; ++kc) {
                loadB(ct, kc * 128);
                #pragma unroll
                for (int ks = 0; ks < 4; ++ks) {
                    const int ksg = kc * 4 + ks;
                    short8 af[4];
                    #pragma unroll
                    for (int r = 0; r < 4; ++r)
                        af[r] = *(const short8*)(smem + (r * KS_TOT + ksg) * 1024 + loff);
                    #pragma unroll
                    for (int r = 0; r < 4; ++r)
                        #pragma unroll
                        for (int c = 0; c < 2; ++c)
                            acc[r][c] = __builtin_amdgcn_mfma_f32_16x16x32_bf16(af[r], breg[c][ks], acc[r][c], 0, 0, 0);
                }
            }
            epilogue(ct);
        }
    } else {
        const int akoff = wv * 32 + kq4 * 8;
        auto stageChunk = [&](int kcb, int b, const short8* pre) {
            const int c0k = kcb + akoff;
            float sc8[8], sh8[8];
            if (XF >= 2) {
                #pragma unroll
                for (int j = 0; j < 8; ++j) {
                    sc8[j] = pCoef[c0k + j];
                    sh8[j] = pCoef[K + c0k + j];
                }
            }
            #pragma unroll
            for (int i = 0; i < 4; ++i) {
                short8 t = pre ? pre[i]
                              : *(const short8*)((const unsigned short*)Av + (size_t)rowg[i] * K + c0k);
                short8 val = (XF == 2) ? xf2(t, sc8, sh8) : t;
                *(short8*)(smem + (b * 16 + i * 4 + wv) * 1024 + woff) = val;
            }
        };
        stageChunk(0, 0, nullptr);
        __syncthreads();
        #pragma unroll
        for (int r = 0; r < 4; ++r)
            #pragma unroll
            for (int c = 0; c < 2; ++c) acc[r][c] = f32x4{0.f, 0.f, 0.f, 0.f};
        #pragma unroll
        for (int kc = 0; kc < NKC; ++kc) {
            const int cur = kc & 1;
            loadB(0, kc * 128);
            short8 anext[4];
            if (kc + 1 < NKC) {
                const int c0k = (kc + 1) * 128 + akoff;
                #pragma unroll
                for (int i = 0; i < 4; ++i)
                    anext[i] = *(const short8*)((const unsigned short*)Av + (size_t)rowg[i] * K + c0k);
            }
            #pragma unroll
            for (int ks = 0; ks < 4; ++ks) {
                short8 af[4];
                #pragma unroll
                for (int r = 0; r < 4; ++r)
                    af[r] = *(const short8*)(smem + (cur * 16 + r * 4 + ks) * 1024 + loff);
                #pragma unroll
                for (int r = 0; r < 4; ++r)
                    #pragma unroll
                    for (int c = 0; c < 2; ++c)
                        acc[r][c] = __builtin_amdgcn_mfma_f32_16x16x32_bf16(af[r], breg[c][ks], acc[r][c], 0, 0, 0);
            }
            if (kc + 1 < NKC) {
                stageChunk((kc + 1) * 128, cur ^ 1, anext);
                __syncthreads();
            }
        }
        epilogue(0);
    }

    // ---- ticket: last block folds partials -> coef ----
    if (part != nullptr) {
        __threadfence();
        __syncthreads();
        if (tid == 0) {
            int old = atomicAdd(ticket, 1);
            lastFlag = (old == (int)gridDim.x - 1);
        }
        __syncthreads();
        if (lastFlag)
            coef_fold(part, gArr, bArr, coefOut, M, invN, tid);
    }
}

// ---------------- fused: encoder GEMM (blocks < rb) + CSR place (rest) ------
__global__ __launch_bounds__(256, 5)
void enc_place_kernel(const float* __restrict__ Av,
                      const unsigned short* __restrict__ Wp,
                      const float* __restrict__ bias,
                      float* __restrict__ part,
                      unsigned short* __restrict__ C, int nrows, int rb,
                      const int* __restrict__ ei, int* __restrict__ cursor,
                      void* __restrict__ ssrcv, int E, int useU16,
                      const float* __restrict__ gArr, const float* __restrict__ bArr,
                      float* __restrict__ coefOut, int* __restrict__ ticket,
                      float invN)
{
    __shared__ __align__(16) char smem[16384];
    __shared__ int lastFlag;
    if ((int)blockIdx.x >= rb) {
        const int e = (blockIdx.x - rb) * 256 + threadIdx.x;
        if (e < E) {
            int pos = atomicAdd(&cursor[ei[E + e]], 1);
            if (useU16) ((unsigned short*)ssrcv)[pos] = (unsigned short)ei[e];
            else        ((int*)ssrcv)[pos] = ei[e];
        }
        return;
    }
    const int tid = threadIdx.x;
    const int l = tid & 63, wv = tid >> 6;
    const int gr0 = blockIdx.x * 64;
    const int kq4 = l & 3, rloc = l >> 2;
    const int woff = ((kq4 * 16 + rloc) * 16) ^ (kq4 << 5);
    const int loff = (l * 16) ^ ((l >> 4) << 5);
    const int lrow = l & 15, kg = l >> 4;
    const int akoff = wv * 32 + kq4 * 8;

    int rowg[4];
    #pragma unroll
    for (int i = 0; i < 4; ++i) {
        int rg = gr0 + i * 16 + rloc;
        rowg[i] = rg < nrows ? rg : nrows - 1;
    }
    #pragma unroll
    for (int i = 0; i < 4; ++i) {
        const float* p = Av + (size_t)rowg[i] * 128 + akoff;
        f32x4 u0 = *(const f32x4*)p;
        f32x4 u1 = *(const f32x4*)(p + 4);
        short8 val;
        #pragma unroll
        for (int j = 0; j < 4; ++j) {
            val[j]     = (short)f2bf(u0[j]);
            val[j + 4] = (short)f2bf(u1[j]);
        }
        *(short8*)(smem + (i * 4 + wv) * 1024 + woff) = val;
    }
    __syncthreads();

    short8 breg[2][4];
    #pragma unroll
    for (int c = 0; c < 2; ++c) {
        const int col = (wv * 2 + c) * 16 + lrow;
        const unsigned short* bp = Wp + (size_t)col * 128 + kg * 8;
        #pragma unroll
        for (int ks = 0; ks < 4; ++ks) breg[c][ks] = *(const short8*)(bp + ks * 32);
    }
    f32x4 acc[4][2];
    #pragma unroll
    for (int r = 0; r < 4; ++r)
        #pragma unroll
        for (int c = 0; c < 2; ++c) acc[r][c] = f32x4{0.f, 0.f, 0.f, 0.f};
    #pragma unroll
    for (int ks = 0; ks < 4; ++ks) {
        short8 af[4];
        #pragma unroll
        for (int r = 0; r < 4; ++r)
            af[r] = *(const short8*)(smem + (r * 4 + ks) * 1024 + loff);
        #pragma unroll
        for (int r = 0; r < 4; ++r)
            #pragma unroll
            for (int c = 0; c < 2; ++c)
                acc[r][c] = __builtin_amdgcn_mfma_f32_16x16x32_bf16(af[r], breg[c][ks], acc[r][c], 0, 0, 0);
    }
    __syncthreads();
    #pragma unroll
    for (int c = 0; c < 2; ++c) {
        const int col = (wv * 2 + c) * 16 + lrow;
        const float bc = bias[col];
        float s = 0.f, q = 0.f;
        #pragma unroll
        for (int r = 0; r < 4; ++r)
            #pragma unroll
            for (int i = 0; i < 4; ++i) {
                const int rl = r * 16 + kg * 4 + i;
                const float v = acc[r][c][i] + bc;
                if (gr0 + rl < nrows) { s += v; q += v * v; }
                *(unsigned short*)(smem + rl * 256 + ((col * 2) ^ ((rl & 7) << 4))) = f2bf(v);
            }
        s += __shfl_xor(s, 16); s += __shfl_xor(s, 32);
        q += __shfl_xor(q, 16); q += __shfl_xor(q, 32);
        if (kg == 0) {
            float* ps = part + (size_t)(blockIdx.x & (NPART - 1)) * 256;
            atomicAdd(&ps[col], s);
            atomicAdd(&ps[128 + col], q);
        }
    }
    __syncthreads();
    #pragma unroll
    for (int j = 0; j < 4; ++j) {
        const int lin = j * 256 + tid;
        const int rl = lin >> 4, chunk = lin & 15;
        const int row = gr0 + rl;
        if (row < nrows) {
            short8 vv = *(const short8*)(smem + rl * 256 + ((chunk * 16) ^ ((rl & 7) << 4)));
            *(short8*)(C + (size_t)row * 128 + chunk * 8) = vv;
        }
    }
    // ---- ticket: last GEMM block folds partials -> coef (rb stat blocks) ----
    __threadfence();
    __syncthreads();
    if (tid == 0) {
        int old = atomicAdd(ticket, 1);
        lastFlag = (old == rb - 1);
    }
    __syncthreads();
    if (lastFlag)
        coef_fold(part, gArr, bArr, coefOut, 128, invN, tid);
}

// ---------------- fused: weight pack (blocks < 448) + degree hist -----------
struct PackDesc { const float* src; unsigned short* dst; int K; int M; };
struct Pack7 { PackDesc d[7]; };
__global__ void pack_hist_kernel(Pack7 p, const int* __restrict__ ei,
                                 int* __restrict__ cnt, int E)
{
    if (blockIdx.x < 448) {
        const PackDesc d = p.d[blockIdx.x >> 6];
        const int total = d.K * d.M;
        for (int idx = (blockIdx.x & 63) * 256 + threadIdx.x; idx < total;
             idx += 64 * 256) {
            const int k = idx / d.M;
            const int m = idx - k * d.M;
            d.dst[(size_t)m * d.K + k] = f2bf(d.src[idx]);
        }
    } else {
        const int e = (blockIdx.x - 448) * 256 + threadIdx.x;
        if (e < E) atomicAdd(&cnt[ei[E + e]], 1);
    }
}

// ---------------- scans ------------------------------------------------------
__global__ void scan_reduce(const int* __restrict__ cnt, int* __restrict__ blksum, int n)
{
    __shared__ int s[256];
    int t = threadIdx.x;
    int i = blockIdx.x * 256 + t;
    s[t] = i < n ? cnt[i] : 0;
    __syncthreads();
    for (int d = 128; d > 0; d >>= 1) {
        if (t < d) s[t] += s[t + d];
        __syncthreads();
    }
    if (t == 0) blksum[blockIdx.x] = s[0];
}

__global__ void scan_top(int* __restrict__ blksum, int nb)
{
    __shared__ int s[256];
    int t = threadIdx.x;
    int v = t < nb ? blksum[t] : 0;
    s[t] = v;
    __syncthreads();
    for (int d = 1; d < 256; d <<= 1) {
        int u = (t >= d) ? s[t - d] : 0;
        __syncthreads();
        s[t] += u;
        __syncthreads();
    }
    if (t < nb) blksum[t] = s[t] - v;   // exclusive
}

__global__ void scan_apply(const int* __restrict__ cnt, const int* __restrict__ blksum,
                           int* __restrict__ offs, int* __restrict__ cursor, int n)
{
    __shared__ int s[256];
    int t = threadIdx.x;
    int i = blockIdx.x * 256 + t;
    int v = i < n ? cnt[i] : 0;
    s[t] = v;
    __syncthreads();
    for (int d = 1; d < 256; d <<= 1) {
        int u = (t >= d) ? s[t - d] : 0;
        __syncthreads();
        s[t] += u;
        __syncthreads();
    }
    int excl = s[t] - v + blksum[blockIdx.x];
    if (i < n) { offs[i] = excl; cursor[i] = excl; }
}

// ---------------- GIN gather with fused BN0 (precomputed coefs) -------------
template<typename IDX>
__global__ __launch_bounds__(256)
void gather_kernel(const unsigned short* __restrict__ T0,
                   const float* __restrict__ coef,   // [sc(128)|sh(128)]
                   const IDX* __restrict__ ssrc, const int* __restrict__ offs,
                   const int* __restrict__ cnt,
                   unsigned short* __restrict__ Zb, int N)
{
    const int wave = threadIdx.x >> 6;
    const int lane = threadIdx.x & 63;
    const int node = blockIdx.x * 4 + wave;
    if (node >= N) return;

    unsigned int hv = *(const unsigned int*)(T0 + (size_t)node * 128 + lane * 2);
    float a0 = bf2f((unsigned short)hv);
    float a1 = bf2f((unsigned short)(hv >> 16));

    const int off = offs[node];
    const int deg = cnt[node];
    for (int base = 0; base < deg; base += 64) {
        int m = deg - base;
        if (m > 64) m = 64;
        int idx = (base + lane < deg) ? (int)ssrc[off + base + lane] : 0;
        int k = 0;
        for (; k + 1 < m; k += 2) {
            int s0 = __shfl(idx, k);
            int s1 = __shfl(idx, k + 1);
            unsigned int v0 = *(const unsigned int*)(T0 + (size_t)s0 * 128 + lane * 2);
            unsigned int v1 = *(const unsigned int*)(T0 + (size_t)s1 * 128 + lane * 2);
            a0 += bf2f((unsigned short)v0) + bf2f((unsigned short)v1);
            a1 += bf2f((unsigned short)(v0 >> 16)) + bf2f((unsigned short)(v1 >> 16));
        }
        if (k < m) {
            int s0 = __shfl(idx, k);
            unsigned int v0 = *(const unsigned int*)(T0 + (size_t)s0 * 128 + lane * 2);
            a0 += bf2f((unsigned short)v0);
            a1 += bf2f((unsigned short)(v0 >> 16));
        }
    }
    const int c0 = lane * 2;
    const float dp1 = (float)(deg + 1);
    const float z0 = fmaf(coef[c0], a0, dp1 * coef[128 + c0]);
    const float z1 = fmaf(coef[c0 + 1], a1, dp1 * coef[128 + c0 + 1]);
    unsigned int o = ((unsigned int)f2bf(z1) << 16) | (unsigned int)f2bf(z0);
    *(unsigned int*)(Zb + (size_t)node * 128 + lane * 2) = o;
}

// ---------------- final: out = bn(t6) + h3 (fp32) --------------------------
__global__ void final_kernel(const unsigned short* __restrict__ t6,
                             const float* __restrict__ coef,   // [sc(128)|sh(128)]
                             const unsigned short* __restrict__ h3,
                             float* __restrict__ out, int total4)
{
    int idx = blockIdx.x * blockDim.x + threadIdx.x;
    if (idx >= total4) return;
    const int base = idx * 4;
    const int c0 = base & 127;
    ushort4 tv = *(const ushort4*)(t6 + base);
    ushort4 hv = *(const ushort4*)(h3 + base);
    unsigned short ts[4] = {tv.x, tv.y, tv.z, tv.w};
    unsigned short hs[4] = {hv.x, hv.y, hv.z, hv.w};
    float4 ov;
    float* po = &ov.x;
    #pragma unroll
    for (int j = 0; j < 4; ++j) {
        const int c = c0 + j;
        po[j] = fmaf(coef[c], bf2f(ts[j]), coef[128 + c]) + bf2f(hs[j]);
    }
    *(float4*)(out + base) = ov;
}

extern "C" void kernel_launch(void* const* d_in, const int* in_sizes, int n_in,
                              void* d_out, int out_size, void* d_ws, size_t ws_size,
                              hipStream_t stream)
{
    const float* x     = (const float*)d_in[0];
    const int*   ei    = (const int*)d_in[1];
    const float* enc_W = (const float*)d_in[2];
    const float* enc_b = (const float*)d_in[3];
    const float* bn_g  = (const float*)d_in[4];
    const float* bn_b  = (const float*)d_in[5];
    const float* gW1   = (const float*)d_in[6];
    const float* gb1   = (const float*)d_in[7];
    const float* gg    = (const float*)d_in[8];
    const float* gbb   = (const float*)d_in[9];
    const float* gW2   = (const float*)d_in[10];
    const float* gb2   = (const float*)d_in[11];
    const float* f2W1  = (const float*)d_in[12];
    const float* f2b1  = (const float*)d_in[13];
    const float* f2g1  = (const float*)d_in[14];
    const float* f2bb1 = (const float*)d_in[15];
    const float* f2W2  = (const float*)d_in[16];
    const float* f2b2  = (const float*)d_in[17];
    const float* f2g2  = (const float*)d_in[18];
    const float* f2bb2 = (const float*)d_in[19];
    const float* fnW1  = (const float*)d_in[20];
    const float* fnb1  = (const float*)d_in[21];
    const float* fng1  = (const float*)d_in[22];
    const float* fnbb1 = (const float*)d_in[23];
    const float* fnW2  = (const float*)d_in[24];
    const float* fnb2  = (const float*)d_in[25];
    const float* fng2  = (const float*)d_in[26];
    const float* fnbb2 = (const float*)d_in[27];

    const int D = 128;
    const int N = in_sizes[0] / D;   // 50000
    const int E = in_sizes[1] / 2;   // 640000
    const float invN = 1.0f / (float)N;
    const int useU16 = (N <= 65535);

    // ---- workspace layout ----
    char* w = (char*)d_ws;
    float* c0 = (float*)w;          // coef arrays [sc(W)|sh(W)]
    float* c1 = c0 + 256;
    float* c3 = c1 + 256;           // W=256
    float* c4 = c3 + 512;
    float* c5 = c4 + 256;           // W=512
    float* c6 = c5 + 1024;
    const size_t coefBytes = 2560 * sizeof(float);
    size_t off = coefBytes;

    int* tickets = (int*)(w + off); off += 256;   // 6 tickets (padded)
    float* p0 = (float*)(w + off); off += (size_t)NPART * 256 * 4;
    float* p1 = (float*)(w + off); off += (size_t)NPART * 256 * 4;
    float* p3 = (float*)(w + off); off += (size_t)NPART * 512 * 4;
    float* p4 = (float*)(w + off); off += (size_t)NPART * 256 * 4;
    float* p5 = (float*)(w + off); off += (size_t)NPART * 1024 * 4;
    float* p6 = (float*)(w + off); off += (size_t)NPART * 256 * 4;
    const size_t zeroBytes = 256 + (size_t)NPART * 2560 * 4;

    unsigned short* wpE  = (unsigned short*)(w + off); off += (size_t)128 * 128 * 2;
    unsigned short* wpG1 = (unsigned short*)(w + off); off += (size_t)128 * 128 * 2;
    unsigned short* wpG2 = (unsigned short*)(w + off); off += (size_t)128 * 128 * 2;
    unsigned short* wpF1 = (unsigned short*)(w + off); off += (size_t)128 * 256 * 2;
    unsigned short* wpF2 = (unsigned short*)(w + off); off += (size_t)256 * 128 * 2;
    unsigned short* wpN1 = (unsigned short*)(w + off); off += (size_t)128 * 512 * 2;
    unsigned short* wpN2 = (unsigned short*)(w + off); off += (size_t)512 * 128 * 2;

    unsigned short* P1 = (unsigned short*)(w + off); off += (size_t)N * 128 * 2; // t0,t1,t4,t6
    unsigned short* Zb = (unsigned short*)(w + off); off += (size_t)N * 128 * 2; // Z, t2
    unsigned short* H3 = (unsigned short*)(w + off); off += (size_t)N * 128 * 2; // h3
    unsigned short* T3 = (unsigned short*)(w + off); off += (size_t)N * 256 * 2; // t3
    unsigned short* T5 = (unsigned short*)(w + off); off += (size_t)N * 512 * 2; // t5

    // CSR arrays inside T5 (CSR dead after gather; T5 first written at step 8)
    const int NB = (N + 255) / 256;
    char* csr = (char*)T5;
    int* cnt    = (int*)csr;  csr += (size_t)NB * 256 * 4;
    int* offs   = (int*)csr;  csr += (size_t)NB * 256 * 4;
    int* cursor = (int*)csr;  csr += (size_t)NB * 256 * 4;
    int* blksum = (int*)csr;  csr += 1024;
    void* ssrcv = (void*)csr;

    hipMemsetAsync(tickets, 0, zeroBytes, stream);
    hipMemsetAsync(cnt, 0, (size_t)NB * 256 * 4, stream);

    Pack7 pk;
    pk.d[0] = PackDesc{enc_W, wpE, 128, 128};
    pk.d[1] = PackDesc{gW1, wpG1, 128, 128};
    pk.d[2] = PackDesc{gW2, wpG2, 128, 128};
    pk.d[3] = PackDesc{f2W1, wpF1, 128, 256};
    pk.d[4] = PackDesc{f2W2, wpF2, 256, 128};
    pk.d[5] = PackDesc{fnW1, wpN1, 128, 512};
    pk.d[6] = PackDesc{fnW2, wpN2, 512, 128};

    const int eb  = (E + 255) / 256;
    const int rb  = (N + 63) / 64;
    const int t4a = N * 128 / 4;
    const int ewb = (t4a + 255) / 256;

    // pack + hist (independent) in one launch
    pack_hist_kernel<<<448 + eb, 256, 0, stream>>>(pk, ei, cnt, E);
    scan_reduce<<<NB, 256, 0, stream>>>(cnt, blksum, N);
    scan_top<<<1, 256, 0, stream>>>(blksum, NB);
    scan_apply<<<NB, 256, 0, stream>>>(cnt, blksum, offs, cursor, N);

    // 1) encoder GEMM + CSR place (independent); last GEMM block folds c0
    enc_place_kernel<<<rb + eb, 256, 0, stream>>>(
        x, wpE, enc_b, p0, P1, N, rb, ei, cursor, ssrcv, E, useU16,
        bn_g, bn_b, c0, tickets + 0, invN);
    // 2) Z = bn0(t0 self+agg)                       -> Zb
    if (useU16)
        gather_kernel<unsigned short><<<(N + 3) / 4, 256, 0, stream>>>(
            P1, c0, (const unsigned short*)ssrcv, offs, cnt, Zb, N);
    else
        gather_kernel<unsigned int><<<(N + 3) / 4, 256, 0, stream>>>(
            P1, c0, (const unsigned int*)ssrcv, offs, cnt, Zb, N);
    // 3) t1 = Z @ gW1 + gb1                         -> P1, partials p1 -> c1
    gemmf_kernel<128, 128, 0><<<rb, 256, 0, stream>>>(
        Zb, nullptr, nullptr, nullptr, nullptr, wpG1, gb1, p1, P1, N,
        gg, gbb, c1, tickets + 1, invN);
    // 4) t2 = gelu(bn(t1)) @ gW2 + gb2              -> Zb (no stats)
    gemmf_kernel<128, 128, 2><<<rb, 256, 0, stream>>>(
        P1, c1, nullptr, nullptr, nullptr, wpG2, gb2, nullptr, Zb, N,
        nullptr, nullptr, nullptr, nullptr, invN);
    // 5) t3 = t2 @ f2W1 + f2b1                      -> T3, partials p3 -> c3
    gemmf_kernel<128, 256, 0><<<rb, 256, 0, stream>>>(
        Zb, nullptr, nullptr, nullptr, nullptr, wpF1, f2b1, p3, T3, N,
        f2g1, f2bb1, c3, tickets + 2, invN);
    // 6) t4 = gelu(bn(t3)) @ f2W2 + f2b2            -> P1, partials p4 -> c4
    gemmf_kernel<256, 128, 2><<<rb, 256, 0, stream>>>(
        T3, c3, nullptr, nullptr, nullptr, wpF2, f2b2, p4, P1, N,
        f2g2, f2bb2, c4, tickets + 3, invN);
    // 8) h3 = bn(t4)+t2+x (side-write H3); t5 = h3 @ fnW1 + fnb1 -> T5, p5 -> c5
    gemmf_kernel<128, 512, 3><<<rb, 256, 0, stream>>>(
        P1, c4, Zb, x, H3, wpN1, fnb1, p5, T5, N,
        fng1, fnbb1, c5, tickets + 4, invN);
    // 9) t6 = gelu(bn(t5)) @ fnW2 + fnb2            -> P1, partials p6 -> c6
    gemmf_kernel<512, 128, 2><<<rb, 256, 0, stream>>>(
        T5, c5, nullptr, nullptr, nullptr, wpN2, fnb2, p6, P1, N,
        fng2, fnbb2, c6, tickets + 5, invN);
    // 10) out = bn(t6) + h3                          -> d_out (fp32)
    final_kernel<<<ewb, 256, 0, stream>>>(P1, c6, H3, (float*)d_out, t4a);

    (void)n_in; (void)out_size; (void)ws_size;
}

// Round 14
// 310.662 us; speedup vs baseline: 2.4587x; 2.4587x over previous
//
#include <hip/hip_runtime.h>
#include <hip/hip_bf16.h>

typedef __attribute__((ext_vector_type(8))) short short8;
typedef __attribute__((ext_vector_type(4))) float f32x4;

__device__ __forceinline__ float bf2f(unsigned short u) {
    union { unsigned int i; float f; } c;
    c.i = ((unsigned int)u) << 16;
    return c.f;
}
__device__ __forceinline__ unsigned short f2bf(float f) {
    union { float f; unsigned int i; } c;
    c.f = f;
    unsigned int x = c.i;
    x += 0x7FFFu + ((x >> 16) & 1u);
    return (unsigned short)(x >> 16);
}
// tanh-form GELU via v_exp_f32/v_rcp_f32: |err| < 3.2e-3 abs.
__device__ __forceinline__ float gelu_fast(float x) {
    const float x2 = x * x;
    const float t = x * fmaf(0.0713548163f, x2, 1.5957691216f);
    const float e = __expf(t);
    const float r = __builtin_amdgcn_rcpf(e + 1.0f);
    return fmaf(-x, r, x);
}

#define NPART 64

// ---------------- fused GEMM: C[n,M] = f(A)[n,K] @ W[K,M] + bias ------------
// R11 structure (best: 313us). Hashed partial stats (blockIdx&63).
// pCoef = [sc(K)|sh(K)] precomputed by coef_kernel.
// XF: 0=bf16 pass, 1=fp32 cast, 2=BN+GELUfast,
//     3=BN + res1(bf16) + res2(fp32), side-writing transformed A to h3out.
template<int K, int M, int XF>
__global__ __launch_bounds__(256, (K > 256) ? 4 : 5)
void gemmf_kernel(const void* __restrict__ Av,
                  const float* __restrict__ pCoef,
                  const unsigned short* __restrict__ res1,
                  const float* __restrict__ res2,
                  unsigned short* __restrict__ h3out,
                  const unsigned short* __restrict__ Wp,
                  const float* __restrict__ bias,
                  float* __restrict__ part,          // [NPART][2*M] or null
                  unsigned short* __restrict__ C,
                  int nrows)
{
    constexpr int KS_TOT = K / 32;
    constexpr int NKC    = K / 128;
    constexpr int NCT    = M / 128;
    constexpr bool DBUF  = (K > 256);
    constexpr int NFRAG  = DBUF ? 32 : 4 * KS_TOT;
    __shared__ __align__(16) char smem[NFRAG * 1024 + ((NCT > 1) ? 16384 : 0)];
    char* cbuf = smem + ((NCT > 1) ? NFRAG * 1024 : 0);

    const int tid = threadIdx.x;
    const int l   = tid & 63, wv = tid >> 6;
    const int gr0 = blockIdx.x * 64;
    const int kq4 = l & 3, rloc = l >> 2;
    const int woff = ((kq4 * 16 + rloc) * 16) ^ (kq4 << 5);
    const int loff = (l * 16) ^ ((l >> 4) << 5);

    int rowg[4];
    bool rval[4];
    #pragma unroll
    for (int i = 0; i < 4; ++i) {
        int rg = gr0 + i * 16 + rloc;
        rval[i] = rg < nrows;
        rowg[i] = rval[i] ? rg : nrows - 1;
    }

    f32x4 acc[4][2];
    short8 breg[2][4];

    auto loadB = [&](int ct, int kcb) {
        #pragma unroll
        for (int c = 0; c < 2; ++c) {
            const int col = ct * 128 + (wv * 2 + c) * 16 + (l & 15);
            const unsigned short* bp = Wp + (size_t)col * K + kcb + (l >> 4) * 8;
            #pragma unroll
            for (int ks = 0; ks < 4; ++ks)
                breg[c][ks] = *(const short8*)(bp + ks * 32);
        }
    };

    auto xf2 = [&](short8 t, const float* sc8, const float* sh8) -> short8 {
        short8 val;
        #pragma unroll
        for (int j = 0; j < 8; ++j) {
            float v = fmaf(sc8[j], bf2f((unsigned short)t[j]), sh8[j]);
            val[j] = (short)f2bf(gelu_fast(v));
        }
        return val;
    };

    auto epilogue = [&](int ct) {
        const int lrow = l & 15, kg = l >> 4;
        __syncthreads();
        #pragma unroll
        for (int c = 0; c < 2; ++c) {
            const int col  = (wv * 2 + c) * 16 + lrow;
            const int gcol = ct * 128 + col;
            const float bc = bias[gcol];
            float s = 0.f, q = 0.f;
            #pragma unroll
            for (int r = 0; r < 4; ++r) {
                #pragma unroll
                for (int i = 0; i < 4; ++i) {
                    const int rl = r * 16 + kg * 4 + i;
                    const float v = acc[r][c][i] + bc;
                    if (gr0 + rl < nrows) { s += v; q += v * v; }
                    const int byte = rl * 256 + ((col * 2) ^ ((rl & 7) << 4));
                    *(unsigned short*)(cbuf + byte) = f2bf(v);
                }
            }
            s += __shfl_xor(s, 16); s += __shfl_xor(s, 32);
            q += __shfl_xor(q, 16); q += __shfl_xor(q, 32);
            if (kg == 0 && part != nullptr) {
                float* ps = part + (size_t)(blockIdx.x & (NPART - 1)) * (2 * M);
                atomicAdd(&ps[gcol], s);
                atomicAdd(&ps[M + gcol], q);
            }
        }
        __syncthreads();
        #pragma unroll
        for (int j = 0; j < 4; ++j) {
            const int lin = j * 256 + tid;
            const int rl = lin >> 4, chunk = lin & 15;
            const int row = gr0 + rl;
            if (row < nrows) {
                short8 vv = *(const short8*)(cbuf + rl * 256 + ((chunk * 16) ^ ((rl & 7) << 4)));
                *(short8*)(C + (size_t)row * M + ct * 128 + chunk * 8) = vv;
            }
        }
    };

    if constexpr (!DBUF) {
        #pragma unroll
        for (int h = 0; h < NKC; ++h) {
            const int kst = h * 4 + wv;
            const int c0k = kst * 32 + kq4 * 8;
            float sc8[8], sh8[8];
            if (XF >= 2) {
                #pragma unroll
                for (int j = 0; j < 8; ++j) {
                    sc8[j] = pCoef[c0k + j];
                    sh8[j] = pCoef[K + c0k + j];
                }
            }
            #pragma unroll
            for (int i = 0; i < 4; ++i) {
                const size_t eoff = (size_t)rowg[i] * K + c0k;
                short8 val;
                if (XF == 0) {
                    val = *(const short8*)((const unsigned short*)Av + eoff);
                } else if (XF == 1) {
                    const float* A = (const float*)Av;
                    f32x4 u0 = *(const f32x4*)(A + eoff);
                    f32x4 u1 = *(const f32x4*)(A + eoff + 4);
                    #pragma unroll
                    for (int j = 0; j < 4; ++j) {
                        val[j]     = (short)f2bf(u0[j]);
                        val[j + 4] = (short)f2bf(u1[j]);
                    }
                } else if (XF == 2) {
                    short8 t = *(const short8*)((const unsigned short*)Av + eoff);
                    val = xf2(t, sc8, sh8);
                } else {   // XF==3: h3 = bn(t4) + t2 + x, side-write
                    short8 t = *(const short8*)((const unsigned short*)Av + eoff);
                    short8 u = *(const short8*)(res1 + eoff);
                    f32x4 x0 = *(const f32x4*)(res2 + eoff);
                    f32x4 x1 = *(const f32x4*)(res2 + eoff + 4);
                    #pragma unroll
                    for (int j = 0; j < 8; ++j) {
                        float v = fmaf(sc8[j], bf2f((unsigned short)t[j]), sh8[j]);
                        v += bf2f((unsigned short)u[j]) + ((j < 4) ? x0[j] : x1[j - 4]);
                        val[j] = (short)f2bf(v);
                    }
                    if (rval[i]) *(short8*)(h3out + eoff) = val;
                }
                *(short8*)(smem + (i * KS_TOT + kst) * 1024 + woff) = val;
            }
        }
        __syncthreads();
        #pragma unroll
        for (int ct = 0; ct < NCT; ++ct) {
            #pragma unroll
            for (int r = 0; r < 4; ++r)
                #pragma unroll
                for (int c = 0; c < 2; ++c) acc[r][c] = f32x4{0.f, 0.f, 0.f, 0.f};
            #pragma unroll
            for (int kc = 0; kc < NKC; ++kc) {
                loadB(ct, kc * 128);
                #pragma unroll
                for (int ks = 0; ks < 4; ++ks) {
                    const int ksg = kc * 4 + ks;
                    short8 af[4];
                    #pragma unroll
                    for (int r = 0; r < 4; ++r)
                        af[r] = *(const short8*)(smem + (r * KS_TOT + ksg) * 1024 + loff);
                    #pragma unroll
                    for (int r = 0; r < 4; ++r)
                        #pragma unroll
                        for (int c = 0; c < 2; ++c)
                            acc[r][c] = __builtin_amdgcn_mfma_f32_16x16x32_bf16(af[r], breg[c][ks], acc[r][c], 0, 0, 0);
                }
            }
            epilogue(ct);
        }
    } else {
        const int akoff = wv * 32 + kq4 * 8;
        auto stageChunk = [&](int kcb, int b, const short8* pre) {
            const int c0k = kcb + akoff;
            float sc8[8], sh8[8];
            if (XF >= 2) {
                #pragma unroll
                for (int j = 0; j < 8; ++j) {
                    sc8[j] = pCoef[c0k + j];
                    sh8[j] = pCoef[K + c0k + j];
                }
            }
            #pragma unroll
            for (int i = 0; i < 4; ++i) {
                short8 t = pre ? pre[i]
                              : *(const short8*)((const unsigned short*)Av + (size_t)rowg[i] * K + c0k);
                short8 val = (XF == 2) ? xf2(t, sc8, sh8) : t;
                *(short8*)(smem + (b * 16 + i * 4 + wv) * 1024 + woff) = val;
            }
        };
        stageChunk(0, 0, nullptr);
        __syncthreads();
        #pragma unroll
        for (int r = 0; r < 4; ++r)
            #pragma unroll
            for (int c = 0; c < 2; ++c) acc[r][c] = f32x4{0.f, 0.f, 0.f, 0.f};
        #pragma unroll
        for (int kc = 0; kc < NKC; ++kc) {
            const int cur = kc & 1;
            loadB(0, kc * 128);
            short8 anext[4];
            if (kc + 1 < NKC) {
                const int c0k = (kc + 1) * 128 + akoff;
                #pragma unroll
                for (int i = 0; i < 4; ++i)
                    anext[i] = *(const short8*)((const unsigned short*)Av + (size_t)rowg[i] * K + c0k);
            }
            #pragma unroll
            for (int ks = 0; ks < 4; ++ks) {
                short8 af[4];
                #pragma unroll
                for (int r = 0; r < 4; ++r)
                    af[r] = *(const short8*)(smem + (cur * 16 + r * 4 + ks) * 1024 + loff);
                #pragma unroll
                for (int r = 0; r < 4; ++r)
                    #pragma unroll
                    for (int c = 0; c < 2; ++c)
                        acc[r][c] = __builtin_amdgcn_mfma_f32_16x16x32_bf16(af[r], breg[c][ks], acc[r][c], 0, 0, 0);
            }
            if (kc + 1 < NKC) {
                stageChunk((kc + 1) * 128, cur ^ 1, anext);
                __syncthreads();
            }
        }
        epilogue(0);
    }
}

// ---------------- fused: encoder GEMM (blocks < rb) + CSR place (rest) ------
// place writes u16 indices (N < 65536): halves scatter payload.
__global__ __launch_bounds__(256, 5)
void enc_place_kernel(const float* __restrict__ Av,
                      const unsigned short* __restrict__ Wp,
                      const float* __restrict__ bias,
                      float* __restrict__ part,
                      unsigned short* __restrict__ C, int nrows, int rb,
                      const int* __restrict__ ei, int* __restrict__ cursor,
                      unsigned short* __restrict__ ssrc, int E)
{
    __shared__ __align__(16) char smem[16384];
    if ((int)blockIdx.x >= rb) {
        const int e = (blockIdx.x - rb) * 256 + threadIdx.x;
        if (e < E) {
            int pos = atomicAdd(&cursor[ei[E + e]], 1);
            ssrc[pos] = (unsigned short)ei[e];
        }
        return;
    }
    const int tid = threadIdx.x;
    const int l = tid & 63, wv = tid >> 6;
    const int gr0 = blockIdx.x * 64;
    const int kq4 = l & 3, rloc = l >> 2;
    const int woff = ((kq4 * 16 + rloc) * 16) ^ (kq4 << 5);
    const int loff = (l * 16) ^ ((l >> 4) << 5);
    const int lrow = l & 15, kg = l >> 4;
    const int akoff = wv * 32 + kq4 * 8;

    int rowg[4];
    #pragma unroll
    for (int i = 0; i < 4; ++i) {
        int rg = gr0 + i * 16 + rloc;
        rowg[i] = rg < nrows ? rg : nrows - 1;
    }
    #pragma unroll
    for (int i = 0; i < 4; ++i) {
        const float* p = Av + (size_t)rowg[i] * 128 + akoff;
        f32x4 u0 = *(const f32x4*)p;
        f32x4 u1 = *(const f32x4*)(p + 4);
        short8 val;
        #pragma unroll
        for (int j = 0; j < 4; ++j) {
            val[j]     = (short)f2bf(u0[j]);
            val[j + 4] = (short)f2bf(u1[j]);
        }
        *(short8*)(smem + (i * 4 + wv) * 1024 + woff) = val;
    }
    __syncthreads();

    short8 breg[2][4];
    #pragma unroll
    for (int c = 0; c < 2; ++c) {
        const int col = (wv * 2 + c) * 16 + lrow;
        const unsigned short* bp = Wp + (size_t)col * 128 + kg * 8;
        #pragma unroll
        for (int ks = 0; ks < 4; ++ks) breg[c][ks] = *(const short8*)(bp + ks * 32);
    }
    f32x4 acc[4][2];
    #pragma unroll
    for (int r = 0; r < 4; ++r)
        #pragma unroll
        for (int c = 0; c < 2; ++c) acc[r][c] = f32x4{0.f, 0.f, 0.f, 0.f};
    #pragma unroll
    for (int ks = 0; ks < 4; ++ks) {
        short8 af[4];
        #pragma unroll
        for (int r = 0; r < 4; ++r)
            af[r] = *(const short8*)(smem + (r * 4 + ks) * 1024 + loff);
        #pragma unroll
        for (int r = 0; r < 4; ++r)
            #pragma unroll
            for (int c = 0; c < 2; ++c)
                acc[r][c] = __builtin_amdgcn_mfma_f32_16x16x32_bf16(af[r], breg[c][ks], acc[r][c], 0, 0, 0);
    }
    __syncthreads();
    #pragma unroll
    for (int c = 0; c < 2; ++c) {
        const int col = (wv * 2 + c) * 16 + lrow;
        const float bc = bias[col];
        float s = 0.f, q = 0.f;
        #pragma unroll
        for (int r = 0; r < 4; ++r)
            #pragma unroll
            for (int i = 0; i < 4; ++i) {
                const int rl = r * 16 + kg * 4 + i;
                const float v = acc[r][c][i] + bc;
                if (gr0 + rl < nrows) { s += v; q += v * v; }
                *(unsigned short*)(smem + rl * 256 + ((col * 2) ^ ((rl & 7) << 4))) = f2bf(v);
            }
        s += __shfl_xor(s, 16); s += __shfl_xor(s, 32);
        q += __shfl_xor(q, 16); q += __shfl_xor(q, 32);
        if (kg == 0) {
            float* ps = part + (size_t)(blockIdx.x & (NPART - 1)) * 256;
            atomicAdd(&ps[col], s);
            atomicAdd(&ps[128 + col], q);
        }
    }
    __syncthreads();
    #pragma unroll
    for (int j = 0; j < 4; ++j) {
        const int lin = j * 256 + tid;
        const int rl = lin >> 4, chunk = lin & 15;
        const int row = gr0 + rl;
        if (row < nrows) {
            short8 vv = *(const short8*)(smem + rl * 256 + ((chunk * 16) ^ ((rl & 7) << 4)));
            *(short8*)(C + (size_t)row * 128 + chunk * 8) = vv;
        }
    }
}

// ---------------- coef: fold 64 partials -> per-column (sc, sh) -------------
__global__ void coef_kernel(const float* __restrict__ part,
                            const float* __restrict__ g, const float* __restrict__ b,
                            float* __restrict__ scsh, int W, float invN)
{
    int i = blockIdx.x * blockDim.x + threadIdx.x;
    if (i >= W) return;
    float s = 0.f, q = 0.f;
    #pragma unroll 8
    for (int r = 0; r < NPART; ++r) {
        s += part[(size_t)r * 2 * W + i];
        q += part[(size_t)r * 2 * W + W + i];
    }
    const float mean = s * invN;
    const float var  = q * invN - mean * mean;
    const float sc   = g[i] * rsqrtf(var + 1e-5f);
    scsh[i] = sc;
    scsh[W + i] = b[i] - mean * sc;
}

// ---------------- fused: weight pack (blocks < 448) + degree hist -----------
struct PackDesc { const float* src; unsigned short* dst; int K; int M; };
struct Pack7 { PackDesc d[7]; };
__global__ void pack_hist_kernel(Pack7 p, const int* __restrict__ ei,
                                 int* __restrict__ cnt, int E)
{
    if (blockIdx.x < 448) {
        const PackDesc d = p.d[blockIdx.x >> 6];
        const int total = d.K * d.M;
        for (int idx = (blockIdx.x & 63) * 256 + threadIdx.x; idx < total;
             idx += 64 * 256) {
            const int k = idx / d.M;
            const int m = idx - k * d.M;
            d.dst[(size_t)m * d.K + k] = f2bf(d.src[idx]);
        }
    } else {
        const int e = (blockIdx.x - 448) * 256 + threadIdx.x;
        if (e < E) atomicAdd(&cnt[ei[E + e]], 1);
    }
}

// ---------------- scans ------------------------------------------------------
__global__ void scan_reduce(const int* __restrict__ cnt, int* __restrict__ blksum, int n)
{
    __shared__ int s[256];
    int t = threadIdx.x;
    int i = blockIdx.x * 256 + t;
    s[t] = i < n ? cnt[i] : 0;
    __syncthreads();
    for (int d = 128; d > 0; d >>= 1) {
        if (t < d) s[t] += s[t + d];
        __syncthreads();
    }
    if (t == 0) blksum[blockIdx.x] = s[0];
}

__global__ void scan_top(int* __restrict__ blksum, int nb)
{
    __shared__ int s[256];
    int t = threadIdx.x;
    int v = t < nb ? blksum[t] : 0;
    s[t] = v;
    __syncthreads();
    for (int d = 1; d < 256; d <<= 1) {
        int u = (t >= d) ? s[t - d] : 0;
        __syncthreads();
        s[t] += u;
        __syncthreads();
    }
    if (t < nb) blksum[t] = s[t] - v;   // exclusive
}

__global__ void scan_apply(const int* __restrict__ cnt, const int* __restrict__ blksum,
                           int* __restrict__ offs, int* __restrict__ cursor, int n)
{
    __shared__ int s[256];
    int t = threadIdx.x;
    int i = blockIdx.x * 256 + t;
    int v = i < n ? cnt[i] : 0;
    s[t] = v;
    __syncthreads();
    for (int d = 1; d < 256; d <<= 1) {
        int u = (t >= d) ? s[t - d] : 0;
        __syncthreads();
        s[t] += u;
        __syncthreads();
    }
    int excl = s[t] - v + blksum[blockIdx.x];
    if (i < n) { offs[i] = excl; cursor[i] = excl; }
}

// ---------------- GIN gather with fused BN0 (precomputed coefs) -------------
__global__ __launch_bounds__(256)
void gather_kernel(const unsigned short* __restrict__ T0,
                   const float* __restrict__ coef,   // [sc(128)|sh(128)]
                   const unsigned short* __restrict__ ssrc,
                   const int* __restrict__ offs,
                   const int* __restrict__ cnt,
                   unsigned short* __restrict__ Zb, int N)
{
    const int wave = threadIdx.x >> 6;
    const int lane = threadIdx.x & 63;
    const int node = blockIdx.x * 4 + wave;
    if (node >= N) return;

    unsigned int hv = *(const unsigned int*)(T0 + (size_t)node * 128 + lane * 2);
    float a0 = bf2f((unsigned short)hv);
    float a1 = bf2f((unsigned short)(hv >> 16));

    const int off = offs[node];
    const int deg = cnt[node];
    for (int base = 0; base < deg; base += 64) {
        int m = deg - base;
        if (m > 64) m = 64;
        int idx = (base + lane < deg) ? (int)ssrc[off + base + lane] : 0;
        int k = 0;
        for (; k + 1 < m; k += 2) {
            int s0 = __shfl(idx, k);
            int s1 = __shfl(idx, k + 1);
            unsigned int v0 = *(const unsigned int*)(T0 + (size_t)s0 * 128 + lane * 2);
            unsigned int v1 = *(const unsigned int*)(T0 + (size_t)s1 * 128 + lane * 2);
            a0 += bf2f((unsigned short)v0) + bf2f((unsigned short)v1);
            a1 += bf2f((unsigned short)(v0 >> 16)) + bf2f((unsigned short)(v1 >> 16));
        }
        if (k < m) {
            int s0 = __shfl(idx, k);
            unsigned int v0 = *(const unsigned int*)(T0 + (size_t)s0 * 128 + lane * 2);
            a0 += bf2f((unsigned short)v0);
            a1 += bf2f((unsigned short)(v0 >> 16));
        }
    }
    const int c0 = lane * 2;
    const float dp1 = (float)(deg + 1);
    const float z0 = fmaf(coef[c0], a0, dp1 * coef[128 + c0]);
    const float z1 = fmaf(coef[c0 + 1], a1, dp1 * coef[128 + c0 + 1]);
    unsigned int o = ((unsigned int)f2bf(z1) << 16) | (unsigned int)f2bf(z0);
    *(unsigned int*)(Zb + (size_t)node * 128 + lane * 2) = o;
}

// ---------------- final: out = bn(t6) + h3 (fp32) --------------------------
__global__ void final_kernel(const unsigned short* __restrict__ t6,
                             const float* __restrict__ coef,   // [sc(128)|sh(128)]
                             const unsigned short* __restrict__ h3,
                             float* __restrict__ out, int total4)
{
    int idx = blockIdx.x * blockDim.x + threadIdx.x;
    if (idx >= total4) return;
    const int base = idx * 4;
    const int c0 = base & 127;
    ushort4 tv = *(const ushort4*)(t6 + base);
    ushort4 hv = *(const ushort4*)(h3 + base);
    unsigned short ts[4] = {tv.x, tv.y, tv.z, tv.w};
    unsigned short hs[4] = {hv.x, hv.y, hv.z, hv.w};
    float4 ov;
    float* po = &ov.x;
    #pragma unroll
    for (int j = 0; j < 4; ++j) {
        const int c = c0 + j;
        po[j] = fmaf(coef[c], bf2f(ts[j]), coef[128 + c]) + bf2f(hs[j]);
    }
    *(float4*)(out + base) = ov;
}

extern "C" void kernel_launch(void* const* d_in, const int* in_sizes, int n_in,
                              void* d_out, int out_size, void* d_ws, size_t ws_size,
                              hipStream_t stream)
{
    const float* x     = (const float*)d_in[0];
    const int*   ei    = (const int*)d_in[1];
    const float* enc_W = (const float*)d_in[2];
    const float* enc_b = (const float*)d_in[3];
    const float* bn_g  = (const float*)d_in[4];
    const float* bn_b  = (const float*)d_in[5];
    const float* gW1   = (const float*)d_in[6];
    const float* gb1   = (const float*)d_in[7];
    const float* gg    = (const float*)d_in[8];
    const float* gbb   = (const float*)d_in[9];
    const float* gW2   = (const float*)d_in[10];
    const float* gb2   = (const float*)d_in[11];
    const float* f2W1  = (const float*)d_in[12];
    const float* f2b1  = (const float*)d_in[13];
    const float* f2g1  = (const float*)d_in[14];
    const float* f2bb1 = (const float*)d_in[15];
    const float* f2W2  = (const float*)d_in[16];
    const float* f2b2  = (const float*)d_in[17];
    const float* f2g2  = (const float*)d_in[18];
    const float* f2bb2 = (const float*)d_in[19];
    const float* fnW1  = (const float*)d_in[20];
    const float* fnb1  = (const float*)d_in[21];
    const float* fng1  = (const float*)d_in[22];
    const float* fnbb1 = (const float*)d_in[23];
    const float* fnW2  = (const float*)d_in[24];
    const float* fnb2  = (const float*)d_in[25];
    const float* fng2  = (const float*)d_in[26];
    const float* fnbb2 = (const float*)d_in[27];

    const int D = 128;
    const int N = in_sizes[0] / D;   // 50000
    const int E = in_sizes[1] / 2;   // 640000
    const float invN = 1.0f / (float)N;

    // ---- workspace layout ----
    char* w = (char*)d_ws;
    float* c0 = (float*)w;          // coef arrays [sc(W)|sh(W)]
    float* c1 = c0 + 256;
    float* c3 = c1 + 256;           // W=256
    float* c4 = c3 + 512;
    float* c5 = c4 + 256;           // W=512
    float* c6 = c5 + 1024;
    const size_t coefBytes = 2560 * sizeof(float);
    size_t off = coefBytes;

    float* p0 = (float*)(w + off); off += (size_t)NPART * 256 * 4;
    float* p1 = (float*)(w + off); off += (size_t)NPART * 256 * 4;
    float* p3 = (float*)(w + off); off += (size_t)NPART * 512 * 4;
    float* p4 = (float*)(w + off); off += (size_t)NPART * 256 * 4;
    float* p5 = (float*)(w + off); off += (size_t)NPART * 1024 * 4;
    float* p6 = (float*)(w + off); off += (size_t)NPART * 256 * 4;
    const size_t partBytes = (size_t)NPART * 2560 * 4;

    unsigned short* wpE  = (unsigned short*)(w + off); off += (size_t)128 * 128 * 2;
    unsigned short* wpG1 = (unsigned short*)(w + off); off += (size_t)128 * 128 * 2;
    unsigned short* wpG2 = (unsigned short*)(w + off); off += (size_t)128 * 128 * 2;
    unsigned short* wpF1 = (unsigned short*)(w + off); off += (size_t)128 * 256 * 2;
    unsigned short* wpF2 = (unsigned short*)(w + off); off += (size_t)256 * 128 * 2;
    unsigned short* wpN1 = (unsigned short*)(w + off); off += (size_t)128 * 512 * 2;
    unsigned short* wpN2 = (unsigned short*)(w + off); off += (size_t)512 * 128 * 2;

    unsigned short* P1 = (unsigned short*)(w + off); off += (size_t)N * 128 * 2; // t0,t1,t4,t6
    unsigned short* Zb = (unsigned short*)(w + off); off += (size_t)N * 128 * 2; // Z, t2
    unsigned short* H3 = (unsigned short*)(w + off); off += (size_t)N * 128 * 2; // h3
    unsigned short* T3 = (unsigned short*)(w + off); off += (size_t)N * 256 * 2; // t3
    unsigned short* T5 = (unsigned short*)(w + off); off += (size_t)N * 512 * 2; // t5

    // CSR arrays inside T5 (CSR dead after gather; T5 first written at step 8)
    const int NB = (N + 255) / 256;
    char* csr = (char*)T5;
    int* cnt    = (int*)csr;  csr += (size_t)NB * 256 * 4;
    int* offs   = (int*)csr;  csr += (size_t)NB * 256 * 4;
    int* cursor = (int*)csr;  csr += (size_t)NB * 256 * 4;
    int* blksum = (int*)csr;  csr += 1024;
    unsigned short* ssrc = (unsigned short*)csr;

    hipMemsetAsync(p0, 0, partBytes, stream);
    hipMemsetAsync(cnt, 0, (size_t)NB * 256 * 4, stream);

    Pack7 pk;
    pk.d[0] = PackDesc{enc_W, wpE, 128, 128};
    pk.d[1] = PackDesc{gW1, wpG1, 128, 128};
    pk.d[2] = PackDesc{gW2, wpG2, 128, 128};
    pk.d[3] = PackDesc{f2W1, wpF1, 128, 256};
    pk.d[4] = PackDesc{f2W2, wpF2, 256, 128};
    pk.d[5] = PackDesc{fnW1, wpN1, 128, 512};
    pk.d[6] = PackDesc{fnW2, wpN2, 512, 128};

    const int eb  = (E + 255) / 256;
    const int rb  = (N + 63) / 64;
    const int t4a = N * 128 / 4;
    const int ewb = (t4a + 255) / 256;

    // pack + hist (independent) in one launch
    pack_hist_kernel<<<448 + eb, 256, 0, stream>>>(pk, ei, cnt, E);
    scan_reduce<<<NB, 256, 0, stream>>>(cnt, blksum, N);
    scan_top<<<1, 256, 0, stream>>>(blksum, NB);
    scan_apply<<<NB, 256, 0, stream>>>(cnt, blksum, offs, cursor, N);

    // 1) encoder GEMM + CSR place (independent) in one launch
    enc_place_kernel<<<rb + eb, 256, 0, stream>>>(
        x, wpE, enc_b, p0, P1, N, rb, ei, cursor, ssrc, E);
    coef_kernel<<<1, 256, 0, stream>>>(p0, bn_g, bn_b, c0, 128, invN);
    // 2) Z = bn0(t0 self+agg)                       -> Zb
    gather_kernel<<<(N + 3) / 4, 256, 0, stream>>>(
        P1, c0, ssrc, offs, cnt, Zb, N);
    // 3) t1 = Z @ gW1 + gb1                         -> P1, partials p1
    gemmf_kernel<128, 128, 0><<<rb, 256, 0, stream>>>(
        Zb, nullptr, nullptr, nullptr, nullptr, wpG1, gb1, p1, P1, N);
    coef_kernel<<<1, 256, 0, stream>>>(p1, gg, gbb, c1, 128, invN);
    // 4) t2 = gelu(bn(t1)) @ gW2 + gb2              -> Zb (no stats)
    gemmf_kernel<128, 128, 2><<<rb, 256, 0, stream>>>(
        P1, c1, nullptr, nullptr, nullptr, wpG2, gb2, nullptr, Zb, N);
    // 5) t3 = t2 @ f2W1 + f2b1                      -> T3, partials p3
    gemmf_kernel<128, 256, 0><<<rb, 256, 0, stream>>>(
        Zb, nullptr, nullptr, nullptr, nullptr, wpF1, f2b1, p3, T3, N);
    coef_kernel<<<1, 256, 0, stream>>>(p3, f2g1, f2bb1, c3, 256, invN);
    // 6) t4 = gelu(bn(t3)) @ f2W2 + f2b2            -> P1, partials p4
    gemmf_kernel<256, 128, 2><<<rb, 256, 0, stream>>>(
        T3, c3, nullptr, nullptr, nullptr, wpF2, f2b2, p4, P1, N);
    coef_kernel<<<1, 256, 0, stream>>>(p4, f2g2, f2bb2, c4, 128, invN);
    // 8) h3 = bn(t4)+t2+x (side-write H3); t5 = h3 @ fnW1 + fnb1 -> T5, p5
    gemmf_kernel<128, 512, 3><<<rb, 256, 0, stream>>>(
        P1, c4, Zb, x, H3, wpN1, fnb1, p5, T5, N);
    coef_kernel<<<2, 256, 0, stream>>>(p5, fng1, fnbb1, c5, 512, invN);
    // 9) t6 = gelu(bn(t5)) @ fnW2 + fnb2            -> P1, partials p6
    gemmf_kernel<512, 128, 2><<<rb, 256, 0, stream>>>(
        T5, c5, nullptr, nullptr, nullptr, wpN2, fnb2, p6, P1, N);
    coef_kernel<<<1, 256, 0, stream>>>(p6, fng2, fnbb2, c6, 128, invN);
    // 10) out = bn(t6) + h3                          -> d_out (fp32)
    final_kernel<<<ewb, 256, 0, stream>>>(P1, c6, H3, (float*)d_out, t4a);

    (void)n_in; (void)out_size; (void)ws_size;
}